// Round 12
// baseline (150.455 us; speedup 1.0000x reference)
//
#include <hip/hip_runtime.h>
#include <math.h>

typedef _Float16 f16;
typedef __attribute__((ext_vector_type(8))) _Float16 f16x8;
typedef __attribute__((ext_vector_type(4))) _Float16 f16x4;
typedef __attribute__((ext_vector_type(4))) float f32x4;

#define NH 12
#define HDIM 64
#define NTOK 197
#define EDIM 768
#define NB 64
#define MROWS (NB*NTOK)   // 12608

__device__ __forceinline__ void wfence() {
    asm volatile("s_waitcnt lgkmcnt(0)" ::: "memory");
    __builtin_amdgcn_sched_barrier(0);
    __builtin_amdgcn_wave_barrier();
}

__device__ __forceinline__ unsigned div14(unsigned n) { return (n * 4682u) >> 16; }  // exact n<=206

__device__ __forceinline__ void gload16(const f16* g, f16* lds_base) {
    __builtin_amdgcn_global_load_lds(
        (const __attribute__((address_space(1))) void*)g,
        (__attribute__((address_space(3))) void*)lds_base, 16, 0, 0);
}

// ---------------------------------------------------------------------------
// Prep: [0,576) weight transpose+f16 | [576,608) static rel-pos tables
// (pre-swizzled: storage col cs holds logical col cs ^ ((row&7)<<3)).
// x conversion is now fused into the QKV GEMM (AF32 path).
// ---------------------------------------------------------------------------
__global__ __launch_bounds__(256) void prep_all(
    const float* __restrict__ wq, const float* __restrict__ wk,
    const float* __restrict__ wv, const float* __restrict__ wp,
    const float* __restrict__ rkv, const float* __restrict__ rkh,
    f16* __restrict__ wqkvT, f16* __restrict__ wpT,
    f16* __restrict__ gA, f16* __restrict__ gt_buf)
{
    __shared__ float T[64][65];
    const int bid = blockIdx.x;
    if (bid < 576) {
        int m = bid / 144, rem = bid - m*144;
        const float* src = (m==0)?wq:(m==1)?wk:(m==2)?wv:wp;
        int k0 = (rem / 12) * 64, n0 = (rem % 12) * 64;
        int cidx = threadIdx.x & 63, r4 = threadIdx.x >> 6;
#pragma unroll
        for (int rr = 0; rr < 16; ++rr) {
            int kl = rr*4 + r4;
            T[kl][cidx] = src[(size_t)(k0+kl)*EDIM + n0 + cidx];
        }
        __syncthreads();
        f16* dst = (m < 3) ? (wqkvT + (size_t)m*EDIM*EDIM) : wpT;
#pragma unroll
        for (int rr = 0; rr < 16; ++rr) {
            int nl = rr*4 + r4;
            dst[(size_t)(n0+nl)*EDIM + k0 + cidx] = (f16)T[cidx][nl];
        }
    } else {
        int t = (bid - 576) * 256 + threadIdx.x;
        const int stride = 32 * 256;
        for (int i = t; i < 272*128; i += stride) {
            int row = i >> 7, cs = i & 127;
            int c = cs ^ ((row & 7) << 3);
            f16 v = (f16)0.f;
            if (c < 64) {
                if (row >= 208 && row < 238)      v = (f16)rkv[(row-208)*64 + c];
                else if (row >= 240 && row < 270) v = (f16)rkh[(row-240)*64 + c];
            } else if (c < 96 && row < 208) {
                int g = c - 64;
                if (row == 0) { if (g == 14 || g == 30) v = (f16)1.f; }
                else if (row <= 196) {
                    int rm = row - 1;
                    int gv = (int)div14((unsigned)rm), gh = rm - gv*14;
                    if (g == gv || g == 16 + gh) v = (f16)1.f;
                }
            }
            gA[i] = v;
        }
        for (int i = t; i < 32*256; i += stride) {
            int g = i >> 8, cs = i & 255;
            int j = cs ^ ((g & 7) << 3);
            f16 v = (f16)0.f;
            if (j >= 1 && j <= 196) {
                int jm = j - 1;
                int gv = (int)div14((unsigned)jm), gh = jm - gv*14;
                if ((g < 14 && gv == g) || (g >= 16 && g < 30 && gh == g - 16))
                    v = (f16)1.f;
            }
            gt_buf[i] = v;
        }
    }
}

// ---------------------------------------------------------------------------
// 256x256-tile f16 MFMA GEMM. AF32=true: A is f32, reg-staged with in-flight
// f32->f16 convert (fuses convert_x); B via global_load_lds. AF32=false:
// both operands via global_load_lds (round-8 proven path).
// ---------------------------------------------------------------------------
template<bool AF32>
__global__ __launch_bounds__(512, 2) void gemm256T(
    const void* __restrict__ Ain, const f16* __restrict__ Bt,
    f16* __restrict__ q_o, f16* __restrict__ k_o, f16* __restrict__ v_o,
    float* __restrict__ p_o, const float* __restrict__ bias, int mode, int nxb)
{
    __shared__ f16 lds[4*16384];

    const int tid = threadIdx.x;
    const int l = tid & 63, w = tid >> 6;
    const int lr = l & 15, lq = l >> 4;
    const int wr = w >> 2, wc = w & 3;

    const int nwg = gridDim.x, orig = blockIdx.x;
    const int xcd = orig & 7, qc = nwg >> 3, rc = nwg & 7;
    const int wgid = (xcd < rc ? xcd*(qc+1) : rc*(qc+1) + (xcd-rc)*qc) + (orig >> 3);
    const int mband = wgid / nxb, nband = wgid - mband*nxb;
    const int m0 = mband << 8, n0 = nband << 8;

    const int scol = (((tid & 7) ^ ((tid >> 3) & 7)) << 3);
    const f16* bG[4];
    const f16* aGh[4];
    const float* aGf[4];
#pragma unroll
    for (int p = 0; p < 4; ++p) {
        int rt = p*64 + (tid >> 3);
        int ra = m0 + rt; if (ra >= MROWS) ra = MROWS - 1;
        if (AF32) aGf[p] = (const float*)Ain + (size_t)ra * EDIM + ((tid & 7) << 3);
        else      aGh[p] = (const f16*)Ain + (size_t)ra * EDIM + scol;
        bG[p] = Bt + (size_t)(n0 + rt) * EDIM + scol;
    }
    const int lbase = w * 512;
    const int dstA = (tid >> 3)*64 + scol;   // + p*4096 + buf*16384

    f32x4 acc[8][4];
#pragma unroll
    for (int mt = 0; mt < 8; ++mt)
#pragma unroll
        for (int nt = 0; nt < 4; ++nt) {
            acc[mt][nt][0]=0.f; acc[mt][nt][1]=0.f;
            acc[mt][nt][2]=0.f; acc[mt][nt][3]=0.f;
        }

    float4 ar0[4], ar1[4];
    // ---- prologue: stage K-tile 0 into buf0 ----
#pragma unroll
    for (int p = 0; p < 4; ++p)
        gload16(bG[p], &lds[32768 + p*4096 + lbase]);
    if (AF32) {
#pragma unroll
        for (int p = 0; p < 4; ++p) {
            ar0[p] = *(const float4*)(aGf[p]);
            ar1[p] = *(const float4*)(aGf[p] + 4);
        }
#pragma unroll
        for (int p = 0; p < 4; ++p) {
            f16x8 h;
            h[0]=(f16)ar0[p].x; h[1]=(f16)ar0[p].y; h[2]=(f16)ar0[p].z; h[3]=(f16)ar0[p].w;
            h[4]=(f16)ar1[p].x; h[5]=(f16)ar1[p].y; h[6]=(f16)ar1[p].z; h[7]=(f16)ar1[p].w;
            *(f16x8*)&lds[p*4096 + dstA] = h;
        }
        __syncthreads();
    } else {
#pragma unroll
        for (int p = 0; p < 4; ++p)
            gload16(aGh[p], &lds[p*4096 + lbase]);
        asm volatile("s_waitcnt vmcnt(0)" ::: "memory");
        __builtin_amdgcn_sched_barrier(0);
        __builtin_amdgcn_s_barrier();
    }

    const int swz = (lr & 7) << 3;
    int cur = 0;
    for (int kt = 0; kt < 12; ++kt) {
        if (kt < 11) {
            const int ko = (kt + 1) * 64;
            const int nb = (cur ^ 1) * 16384;
#pragma unroll
            for (int p = 0; p < 4; ++p)
                gload16(bG[p] + ko, &lds[32768 + nb + p*4096 + lbase]);
            if (AF32) {
#pragma unroll
                for (int p = 0; p < 4; ++p) {
                    ar0[p] = *(const float4*)(aGf[p] + ko);
                    ar1[p] = *(const float4*)(aGf[p] + ko + 4);
                }
            } else {
#pragma unroll
                for (int p = 0; p < 4; ++p)
                    gload16(aGh[p] + ko, &lds[nb + p*4096 + lbase]);
            }
        }
        __builtin_amdgcn_sched_barrier(0);
        const f16* Ab = &lds[cur * 16384];
        const f16* Bb = &lds[32768 + cur * 16384];
#pragma unroll
        for (int ks = 0; ks < 2; ++ks) {
            const int kb = (ks*32 + lq*8) ^ swz;
            f16x8 bf[4];
#pragma unroll
            for (int nt = 0; nt < 4; ++nt)
                bf[nt] = *(const f16x8*)&Bb[(wc*64 + nt*16 + lr)*64 + kb];
#pragma unroll
            for (int mt = 0; mt < 8; ++mt) {
                f16x8 af = *(const f16x8*)&Ab[(wr*128 + mt*16 + lr)*64 + kb];
#pragma unroll
                for (int nt = 0; nt < 4; ++nt)
                    acc[mt][nt] = __builtin_amdgcn_mfma_f32_16x16x32_f16(
                        af, bf[nt], acc[mt][nt], 0, 0, 0);
            }
        }
        if (AF32) {
            if (kt < 11) {
                const int nb = (cur ^ 1) * 16384;
#pragma unroll
                for (int p = 0; p < 4; ++p) {
                    f16x8 h;
                    h[0]=(f16)ar0[p].x; h[1]=(f16)ar0[p].y; h[2]=(f16)ar0[p].z; h[3]=(f16)ar0[p].w;
                    h[4]=(f16)ar1[p].x; h[5]=(f16)ar1[p].y; h[6]=(f16)ar1[p].z; h[7]=(f16)ar1[p].w;
                    *(f16x8*)&lds[nb + p*4096 + dstA] = h;
                }
            }
            __syncthreads();
        } else {
            asm volatile("s_waitcnt vmcnt(0)" ::: "memory");
            __builtin_amdgcn_sched_barrier(0);
            __builtin_amdgcn_s_barrier();
        }
        cur ^= 1;
    }

    if (mode == 0) {
        const int mat   = n0 / EDIM;
        const int hbase = ((n0 % EDIM) >> 6) + wc;
        f16* dst = (mat == 0) ? q_o : (mat == 1) ? k_o : v_o;
        f16* scr = &lds[w * 2304];
#pragma unroll
        for (int mt2 = 0; mt2 < 4; ++mt2) {
#pragma unroll
            for (int mtp = 0; mtp < 2; ++mtp) {
                const int mt = mt2*2 + mtp;
#pragma unroll
                for (int nt = 0; nt < 4; ++nt)
#pragma unroll
                    for (int rg = 0; rg < 4; ++rg)
                        scr[(mtp*16 + lq*4 + rg)*72 + nt*16 + lr] = (f16)acc[mt][nt][rg];
            }
            wfence();
#pragma unroll
            for (int i = 0; i < 4; ++i) {
                int row = (l >> 3) + i*8;
                f16x8 v = *(const f16x8*)&scr[row*72 + (l & 7)*8];
                int R = m0 + wr*128 + mt2*32 + row;
                if (R < MROWS) {
                    int bb = R / NTOK, nn = R - bb*NTOK;
                    *(f16x8*)&dst[((size_t)(bb*NH + hbase)*NTOK + nn)*HDIM + (l & 7)*8] = v;
                }
            }
            wfence();
        }
    } else {
#pragma unroll
        for (int mt = 0; mt < 8; ++mt)
#pragma unroll
            for (int rg = 0; rg < 4; ++rg) {
                int R = m0 + wr*128 + mt*16 + lq*4 + rg;
                if (R < MROWS) {
                    float* base = p_o + (size_t)R * EDIM + n0 + wc*64;
#pragma unroll
                    for (int nt = 0; nt < 4; ++nt) {
                        int c = nt*16 + lr;
                        base[c] = acc[mt][nt][rg] + bias[n0 + wc*64 + c];
                    }
                }
            }
    }
}

// ---------------------------------------------------------------------------
// MFMA fused attention v7: Kle+Gt staged via global_load_lds 1KB chunks
// (linear dest, per-lane pre-swizzled source); Vt value-gather split into
// load-early (regs, overlapped with Kle fetch + P/S/softmax phases) and
// ds_write-late just before a second barrier ahead of PV (T14).
// ---------------------------------------------------------------------------
#define SKE 128
#define SVT 320
#define SGT 256
#define SWS 72
#define ATHR 832

__global__ __launch_bounds__(ATHR, 1) void attn_mfma(
    const f16* __restrict__ q_ws, const f16* __restrict__ k_ws,
    const f16* __restrict__ v_ws,
    const float* __restrict__ rvv, const float* __restrict__ rvh,
    const f16* __restrict__ gA, const f16* __restrict__ gt_buf,
    f16* __restrict__ o_ws)
{
    __shared__ f16 Kle[272*SKE];     // 69632 B = 68 chunks
    __shared__ f16 Vt[64*SVT];       // 40960 B
    __shared__ f16 Gt[32*SGT];       // 16384 B = 16 chunks
    __shared__ f16 WSh[13*16*SWS];   // 29952 B  (total 156928 B)

    const int tid = threadIdx.x;
    const int w = tid >> 6, l = tid & 63;
    const int lr = l & 15, lq = l >> 4;
    const int bh = blockIdx.x;
    const int b = bh / NH, h = bh - b * NH;
    const f16* Qp = q_ws + (size_t)bh * NTOK * HDIM;
    const f16* Kp = k_ws + (size_t)bh * NTOK * HDIM;
    const f16* Vp = v_ws + (size_t)bh * NTOK * HDIM;
    f16* wsh = &WSh[w * 16 * SWS];

    // ---- Kle (68 chunks) + Gt (16 chunks) via global_load_lds ----
    for (int c = w; c < 84; c += 13) {
        f16* ldsb;
        const f16* gsrc;
        if (c < 68) {
            int idx = c*64 + l;
            int row = idx >> 4, cs8 = (idx & 15) << 3;
            ldsb = &Kle[c * 512];
            gsrc = (row < NTOK && cs8 < 64)
                 ? (Kp + row*64 + (cs8 ^ ((row & 7) << 3)))
                 : (gA + row*SKE + cs8);
        } else {
            int c2 = c - 68;
            ldsb = &Gt[c2 * 512];
            gsrc = gt_buf + c2*512 + l*8;
        }
        gload16(gsrc, ldsb);
    }

    // ---- Vt value gather: load early into regs (write deferred) ----
    f16x8 vbuf[4];
#pragma unroll
    for (int it = 0; it < 4; ++it) {
        int idx = tid + it*ATHR;
        if (idx < 8*SVT) {
            int dlow = idx & 7, k = idx >> 3;
            bool isV = (k < NTOK), isA = (k >= 208 && k < 238), isB = (k >= 238 && k < 268);
#pragma unroll
            for (int e = 0; e < 8; ++e) {
                int d = (e << 3) + dlow;
                f16 val = (f16)0.f;
                if (isV)      val = Vp[k*64 + d];
                else if (isA) val = (f16)rvv[(k-208)*64 + d];
                else if (isB) val = (f16)rvh[(k-238)*64 + d];
                vbuf[it][e] = val;
            }
        }
    }

    // ---- Q fragments (pre-barrier for MLP) ----
    const int tt = w;
    const int i0 = tt * 16;
    const int iq = i0 + lr;
    const int iqc = (iq > 196) ? 196 : iq;
    const f16* qsrc = Qp + iqc*64 + lq*8;
    f16x8 qf0 = *(const f16x8*)qsrc;
    f16x8 qf1 = *(const f16x8*)(qsrc + 32);

    __syncthreads();   // drains gload16 + vbuf/Q loads; Kle/Gt ready

    const int src0 = ((l >> 4) & 1) * 32 + lr;
    const int src1 = src0 + 16;
    const int sw = (lr & 7) << 3;

    {
        __builtin_amdgcn_s_setprio(1);
        f32x4 pacc[4];
#pragma unroll
        for (int ct = 0; ct < 4; ++ct) {
            f32x4 a; a[0]=0.f; a[1]=0.f; a[2]=0.f; a[3]=0.f;
            const int krow = (13+ct)*16 + lr;
            f16x8 kf0 = *(f16x8*)&Kle[krow*SKE + ((lq*8) ^ sw)];
            f16x8 kf1 = *(f16x8*)&Kle[krow*SKE + ((32 + lq*8) ^ sw)];
            a = __builtin_amdgcn_mfma_f32_16x16x32_f16(kf0, qf0, a, 0, 0, 0);
            a = __builtin_amdgcn_mfma_f32_16x16x32_f16(kf1, qf1, a, 0, 0, 0);
            pacc[ct] = a;
        }
        __builtin_amdgcn_s_setprio(0);
#pragma unroll
        for (int ct = 0; ct < 4; ++ct)
#pragma unroll
            for (int rg = 0; rg < 4; ++rg)
                wsh[lr*SWS + ct*16 + lq*4 + rg] = (f16)pacc[ct][rg];
        wfence();

        int id_ = 0, ih_ = 0;
        const bool qcls = (iq == 0);
        if (iq > 0) { unsigned v = div14((unsigned)(iq-1)); id_ = (int)v; ih_ = (iq-1) - (int)v*14; }
        f16x8 qcf;
#pragma unroll
        for (int e = 0; e < 8; ++e) {
            int g = lq*8 + e;
            int toff;
            if (g < 14)       toff = qcls ? 0 : (g - id_ + 15);
            else if (g == 14) toff = 0;
            else if (g == 15) toff = 63;
            else if (g < 30)  toff = qcls ? 32 : (32 + (g-16) - ih_ + 15);
            else if (g == 30) toff = 32;
            else              toff = 63;
            qcf[e] = wsh[lr*SWS + toff];
        }

        f32x4 acc[13];
        __builtin_amdgcn_s_setprio(1);
#pragma unroll
        for (int ct = 0; ct < 13; ++ct) {
            f32x4 a; a[0]=0.f; a[1]=0.f; a[2]=0.f; a[3]=0.f;
            const int krow = ct*16 + lr;
            f16x8 kf0 = *(f16x8*)&Kle[krow*SKE + ((lq*8) ^ sw)];
            f16x8 kf1 = *(f16x8*)&Kle[krow*SKE + ((32 + lq*8) ^ sw)];
            f16x8 gf  = *(f16x8*)&Kle[krow*SKE + ((64 + lq*8) ^ sw)];
            a = __builtin_amdgcn_mfma_f32_16x16x32_f16(kf0, qf0, a, 0, 0, 0);
            a = __builtin_amdgcn_mfma_f32_16x16x32_f16(kf1, qf1, a, 0, 0, 0);
            a = __builtin_amdgcn_mfma_f32_16x16x32_f16(gf,  qcf, a, 0, 0, 0);
            acc[ct] = a;
        }
        __builtin_amdgcn_s_setprio(0);

#pragma unroll
        for (int rg = 0; rg < 4; ++rg)
            if (lq*4 + rg > 4) acc[12][rg] = -1e30f;

        float m = -1e30f;
#pragma unroll
        for (int ct = 0; ct < 13; ++ct)
#pragma unroll
            for (int rg = 0; rg < 4; ++rg) m = fmaxf(m, acc[ct][rg]);
        m = fmaxf(m, __shfl_xor(m, 16));
        m = fmaxf(m, __shfl_xor(m, 32));
        const float C1 = 0.125f * 1.44269504088896f;
        const float nm = -m * C1;
        float ssum = 0.f;
#pragma unroll
        for (int ct = 0; ct < 13; ++ct)
#pragma unroll
            for (int rg = 0; rg < 4; ++rg) {
                float p = exp2f(fmaf(acc[ct][rg], C1, nm));
                acc[ct][rg] = p; ssum += p;
            }
        ssum += __shfl_xor(ssum, 16);
        ssum += __shfl_xor(ssum, 32);
        const float inv = 1.f / ssum;
        const float pn00 = acc[0][0] * inv;

        unsigned pk[13][2];
#pragma unroll
        for (int ct = 0; ct < 13; ++ct) {
            union { f16x4 hh; unsigned u[2]; } t;
            t.hh[0] = (f16)(acc[ct][0] * inv);
            t.hh[1] = (f16)(acc[ct][1] * inv);
            t.hh[2] = (f16)(acc[ct][2] * inv);
            t.hh[3] = (f16)(acc[ct][3] * inv);
            pk[ct][0] = t.u[0]; pk[ct][1] = t.u[1];
        }

        f16x8 pa[7];
#pragma unroll
        for (int kc = 0; kc < 7; ++kc) {
            const int ctA = 2*kc;
            const int ctB = (kc == 6) ? 12 : 2*kc + 1;
            unsigned A0 = (unsigned)__shfl((int)pk[ctA][0], src0);
            unsigned A1 = (unsigned)__shfl((int)pk[ctA][1], src0);
            unsigned A2 = (unsigned)__shfl((int)pk[ctA][0], src1);
            unsigned A3 = (unsigned)__shfl((int)pk[ctA][1], src1);
            unsigned B0 = (unsigned)__shfl((int)pk[ctB][0], src0);
            unsigned B1 = (unsigned)__shfl((int)pk[ctB][1], src0);
            unsigned B2 = (unsigned)__shfl((int)pk[ctB][0], src1);
            unsigned B3 = (unsigned)__shfl((int)pk[ctB][1], src1);
            bool hiHalf = (lq >= 2);
            union { unsigned u[4]; f16x8 v; } f;
            f.u[0] = hiHalf ? B0 : A0;
            f.u[1] = hiHalf ? B1 : A1;
            f.u[2] = hiHalf ? B2 : A2;
            f.u[3] = hiHalf ? B3 : A3;
            if (kc == 6 && hiHalf) { f.u[0]=0; f.u[1]=0; f.u[2]=0; f.u[3]=0; }
            pa[kc] = f.v;
        }

        f32x4 gacc[2];
#pragma unroll
        for (int ct = 0; ct < 2; ++ct) { gacc[ct][0]=0.f; gacc[ct][1]=0.f; gacc[ct][2]=0.f; gacc[ct][3]=0.f; }
        __builtin_amdgcn_s_setprio(1);
#pragma unroll
        for (int kc = 0; kc < 7; ++kc) {
#pragma unroll
            for (int ct = 0; ct < 2; ++ct) {
                f16x8 gf = *(f16x8*)&Gt[(ct*16 + lr)*SGT + ((kc*32 + lq*8) ^ sw)];
                gacc[ct] = __builtin_amdgcn_mfma_f32_16x16x32_f16(pa[kc], gf, gacc[ct], 0, 0, 0);
            }
        }
        __builtin_amdgcn_s_setprio(0);

#pragma unroll
        for (int z = 0; z < 2; ++z) {
            int zi = z*64 + l;
            int zr = zi >> 3, zc = (zi & 7) << 3;
            f16x8 zz;
#pragma unroll
            for (int e = 0; e < 8; ++e) zz[e] = (f16)0.f;
            *(f16x8*)&wsh[zr*SWS + zc] = zz;
        }
        wfence();
#pragma unroll
        for (int rg = 0; rg < 4; ++rg) {
            int il = lq*4 + rg;
            int is_ = i0 + il;
            if (lr < 14 && is_ > 0) {
                unsigned v = div14((unsigned)(is_-1));
                int id2 = (int)v, ih2 = (is_-1) - (int)v*14;
                wsh[il*SWS + (lr - id2 + 15)]      = (f16)gacc[0][rg];
                wsh[il*SWS + 30 + (lr - ih2 + 15)] = (f16)gacc[1][rg];
            }
        }
        if (lq == 0 && !(i0 == 0 && lr == 0)) {
            wsh[lr*SWS + 0]  = (f16)pn00;
            wsh[lr*SWS + 30] = (f16)pn00;
        }
        if (i0 == 0) {
            float sv = (lq == 0) ? gacc[0][0] : 0.f;
            float sh = (lq == 0) ? gacc[1][0] : 0.f;
            sv += __shfl_xor(sv, 1); sv += __shfl_xor(sv, 2);
            sv += __shfl_xor(sv, 4); sv += __shfl_xor(sv, 8);
            sh += __shfl_xor(sh, 1); sh += __shfl_xor(sh, 2);
            sh += __shfl_xor(sh, 4); sh += __shfl_xor(sh, 8);
            if (l == 0) {
                wsh[0]  = (f16)(sv + pn00);
                wsh[30] = (f16)(sh + pn00);
            }
        }
        wfence();

        // ---- deferred Vt writes, then block-wide barrier before PV ----
#pragma unroll
        for (int it = 0; it < 4; ++it) {
            int idx = tid + it*ATHR;
            if (idx < 8*SVT) {
                int dlow = idx & 7, k = idx >> 3;
                int kx = k ^ (dlow << 3);
#pragma unroll
                for (int e = 0; e < 8; ++e)
                    Vt[((e << 3) + dlow)*SVT + kx] = vbuf[it][e];
            }
        }
        __syncthreads();

        f16x8 sfr[2];
#pragma unroll
        for (int kc2 = 0; kc2 < 2; ++kc2)
            sfr[kc2] = *(f16x8*)&wsh[lr*SWS + kc2*32 + lq*8];

        f32x4 oacc[4];
#pragma unroll
        for (int ct = 0; ct < 4; ++ct) { oacc[ct][0]=0.f; oacc[ct][1]=0.f; oacc[ct][2]=0.f; oacc[ct][3]=0.f; }
        __builtin_amdgcn_s_setprio(1);
#pragma unroll
        for (int kc = 0; kc < 7; ++kc) {
#pragma unroll
            for (int ct = 0; ct < 4; ++ct) {
                f16x8 vf = *(f16x8*)&Vt[(ct*16 + lr)*SVT + ((kc*32 + lq*8) ^ sw)];
                oacc[ct] = __builtin_amdgcn_mfma_f32_16x16x32_f16(pa[kc], vf, oacc[ct], 0, 0, 0);
            }
        }
#pragma unroll
        for (int kc2 = 0; kc2 < 2; ++kc2) {
#pragma unroll
            for (int ct = 0; ct < 4; ++ct) {
                f16x8 vf = *(f16x8*)&Vt[(ct*16 + lr)*SVT + ((208 + kc2*32 + lq*8) ^ sw)];
                oacc[ct] = __builtin_amdgcn_mfma_f32_16x16x32_f16(sfr[kc2], vf, oacc[ct], 0, 0, 0);
            }
        }
        __builtin_amdgcn_s_setprio(0);

#pragma unroll
        for (int ct = 0; ct < 4; ++ct)
#pragma unroll
            for (int rg = 0; rg < 4; ++rg) {
                int io = i0 + lq*4 + rg;
                if (io < NTOK) {
                    int d = ct*16 + lr;
                    o_ws[((size_t)(b * NTOK + io) * NH + h) * HDIM + d] = (f16)oacc[ct][rg];
                }
            }
    }
}

extern "C" void kernel_launch(void* const* d_in, const int* in_sizes, int n_in,
                              void* d_out, int out_size, void* d_ws, size_t ws_size,
                              hipStream_t stream)
{
    const float* x     = (const float*)d_in[0];
    const float* wq    = (const float*)d_in[1];
    const float* wk    = (const float*)d_in[2];
    const float* wv    = (const float*)d_in[3];
    const float* wproj = (const float*)d_in[4];
    const float* bproj = (const float*)d_in[5];
    const float* rkv   = (const float*)d_in[6];
    const float* rkh   = (const float*)d_in[7];
    const float* rvv   = (const float*)d_in[8];
    const float* rvh   = (const float*)d_in[9];

    f16* ws = (f16*)d_ws;
    const size_t sz = (size_t)MROWS * EDIM;
    f16* qh    = ws;
    f16* kh    = qh + sz;
    f16* vh    = kh + sz;
    f16* oh    = vh + sz;
    f16* wqkvT = oh + sz;                          // 3*768*768
    f16* wpT   = wqkvT + (size_t)3*EDIM*EDIM;      // 768*768
    f16* gA    = wpT   + (size_t)EDIM*EDIM;        // 272*128 (pre-swizzled)
    f16* gtb   = gA    + 272*128;                  // 32*256  (pre-swizzled)

    prep_all<<<608, 256, 0, stream>>>(wq, wk, wv, wproj, rkv, rkh,
                                      wqkvT, wpT, gA, gtb);
    gemm256T<true><<<50*9, 512, 0, stream>>>(x, wqkvT, qh, kh, vh,
                                             nullptr, nullptr, 0, 9);
    attn_mfma<<<NB * NH, ATHR, 0, stream>>>(qh, kh, vh,
                                            rvv, rvh, gA, gtb, oh);
    gemm256T<false><<<50*3, 512, 0, stream>>>(oh, wpT, nullptr, nullptr, nullptr,
                                              (float*)d_out, bproj, 1, 3);
}

// Round 13
// 143.898 us; speedup vs baseline: 1.0456x; 1.0456x over previous
//
#include <hip/hip_runtime.h>
#include <math.h>

typedef _Float16 f16;
typedef __attribute__((ext_vector_type(8))) _Float16 f16x8;
typedef __attribute__((ext_vector_type(4))) _Float16 f16x4;
typedef __attribute__((ext_vector_type(4))) float f32x4;

#define NH 12
#define HDIM 64
#define NTOK 197
#define EDIM 768
#define NB 64
#define MROWS (NB*NTOK)   // 12608

__device__ __forceinline__ void wfence() {
    asm volatile("s_waitcnt lgkmcnt(0)" ::: "memory");
    __builtin_amdgcn_sched_barrier(0);
    __builtin_amdgcn_wave_barrier();
}

__device__ __forceinline__ unsigned div14(unsigned n) { return (n * 4682u) >> 16; }  // exact n<=206

__device__ __forceinline__ void gload16(const f16* g, f16* lds_base) {
    __builtin_amdgcn_global_load_lds(
        (const __attribute__((address_space(1))) void*)g,
        (__attribute__((address_space(3))) void*)lds_base, 16, 0, 0);
}

// ---------------------------------------------------------------------------
// Fused prep: [0,4728) x f32->f16 | [4728,5304) weight transpose+f16 |
// [5304,5336) static rel-pos tables (pre-swizzled: storage col cs holds
// logical col cs ^ ((row&7)<<3)).
// ---------------------------------------------------------------------------
__global__ __launch_bounds__(256) void prep_all(
    const float* __restrict__ x,
    const float* __restrict__ wq, const float* __restrict__ wk,
    const float* __restrict__ wv, const float* __restrict__ wp,
    const float* __restrict__ rkv, const float* __restrict__ rkh,
    f16* __restrict__ xh, f16* __restrict__ wqkvT, f16* __restrict__ wpT,
    f16* __restrict__ gA, f16* __restrict__ gt_buf)
{
    __shared__ float T[64][65];
    const int bid = blockIdx.x;
    if (bid < 4728) {
        int idx = bid * 256 + threadIdx.x;
        const float4* s = (const float4*)x + (size_t)idx * 2;
        float4 a = s[0], b = s[1];
        f16x8 h;
        h[0]=(f16)a.x; h[1]=(f16)a.y; h[2]=(f16)a.z; h[3]=(f16)a.w;
        h[4]=(f16)b.x; h[5]=(f16)b.y; h[6]=(f16)b.z; h[7]=(f16)b.w;
        *(f16x8*)(xh + (size_t)idx * 8) = h;
    } else if (bid < 5304) {
        int b2 = bid - 4728;
        int m = b2 / 144, rem = b2 - m*144;
        const float* src = (m==0)?wq:(m==1)?wk:(m==2)?wv:wp;
        int k0 = (rem / 12) * 64, n0 = (rem % 12) * 64;
        int cidx = threadIdx.x & 63, r4 = threadIdx.x >> 6;
#pragma unroll
        for (int rr = 0; rr < 16; ++rr) {
            int kl = rr*4 + r4;
            T[kl][cidx] = src[(size_t)(k0+kl)*EDIM + n0 + cidx];
        }
        __syncthreads();
        f16* dst = (m < 3) ? (wqkvT + (size_t)m*EDIM*EDIM) : wpT;
#pragma unroll
        for (int rr = 0; rr < 16; ++rr) {
            int nl = rr*4 + r4;
            dst[(size_t)(n0+nl)*EDIM + k0 + cidx] = (f16)T[cidx][nl];
        }
    } else {
        int t = (bid - 5304) * 256 + threadIdx.x;
        const int stride = 32 * 256;
        for (int i = t; i < 272*128; i += stride) {
            int row = i >> 7, cs = i & 127;
            int c = cs ^ ((row & 7) << 3);
            f16 v = (f16)0.f;
            if (c < 64) {
                if (row >= 208 && row < 238)      v = (f16)rkv[(row-208)*64 + c];
                else if (row >= 240 && row < 270) v = (f16)rkh[(row-240)*64 + c];
            } else if (c < 96 && row < 208) {
                int g = c - 64;
                if (row == 0) { if (g == 14 || g == 30) v = (f16)1.f; }
                else if (row <= 196) {
                    int rm = row - 1;
                    int gv = (int)div14((unsigned)rm), gh = rm - gv*14;
                    if (g == gv || g == 16 + gh) v = (f16)1.f;
                }
            }
            gA[i] = v;
        }
        for (int i = t; i < 32*256; i += stride) {
            int g = i >> 8, cs = i & 255;
            int j = cs ^ ((g & 7) << 3);
            f16 v = (f16)0.f;
            if (j >= 1 && j <= 196) {
                int jm = j - 1;
                int gv = (int)div14((unsigned)jm), gh = jm - gv*14;
                if ((g < 14 && gv == g) || (g >= 16 && g < 30 && gh == g - 16))
                    v = (f16)1.f;
            }
            gt_buf[i] = v;
        }
    }
}

// ---------------------------------------------------------------------------
// 256x256-tile f16 MFMA GEMM, 8 waves, dbuf global_load_lds + counted-drain
// pipeline (round-8 proven structure).
// ---------------------------------------------------------------------------
__global__ __launch_bounds__(512, 2) void gemm256(
    const f16* __restrict__ A, const f16* __restrict__ Bt,
    f16* __restrict__ q_o, f16* __restrict__ k_o, f16* __restrict__ v_o,
    float* __restrict__ p_o, const float* __restrict__ bias, int mode, int nxb)
{
    __shared__ f16 lds[4*16384];

    const int tid = threadIdx.x;
    const int l = tid & 63, w = tid >> 6;
    const int lr = l & 15, lq = l >> 4;
    const int wr = w >> 2, wc = w & 3;

    const int nwg = gridDim.x, orig = blockIdx.x;
    const int xcd = orig & 7, qc = nwg >> 3, rc = nwg & 7;
    const int wgid = (xcd < rc ? xcd*(qc+1) : rc*(qc+1) + (xcd-rc)*qc) + (orig >> 3);
    const int mband = wgid / nxb, nband = wgid - mband*nxb;
    const int m0 = mband << 8, n0 = nband << 8;

    const int scol = (((tid & 7) ^ ((tid >> 3) & 7)) << 3);
    const f16* aG[4]; const f16* bG[4];
#pragma unroll
    for (int p = 0; p < 4; ++p) {
        int rt = p*64 + (tid >> 3);
        int ra = m0 + rt; if (ra >= MROWS) ra = MROWS - 1;
        aG[p] = A  + (size_t)ra * EDIM + scol;
        bG[p] = Bt + (size_t)(n0 + rt) * EDIM + scol;
    }
    const int lbase = w * 512;

    f32x4 acc[8][4];
#pragma unroll
    for (int mt = 0; mt < 8; ++mt)
#pragma unroll
        for (int nt = 0; nt < 4; ++nt) {
            acc[mt][nt][0]=0.f; acc[mt][nt][1]=0.f;
            acc[mt][nt][2]=0.f; acc[mt][nt][3]=0.f;
        }

#pragma unroll
    for (int p = 0; p < 4; ++p) {
        gload16(aG[p], &lds[p*4096 + lbase]);
        gload16(bG[p], &lds[32768 + p*4096 + lbase]);
    }
    asm volatile("s_waitcnt vmcnt(0)" ::: "memory");
    __builtin_amdgcn_sched_barrier(0);
    __builtin_amdgcn_s_barrier();

    const int swz = (lr & 7) << 3;
    int cur = 0;
    for (int kt = 0; kt < 12; ++kt) {
        if (kt < 11) {
            const int ko = (kt + 1) * 64;
            const int nb = (cur ^ 1) * 16384;
#pragma unroll
            for (int p = 0; p < 4; ++p) {
                gload16(aG[p] + ko, &lds[nb + p*4096 + lbase]);
                gload16(bG[p] + ko, &lds[32768 + nb + p*4096 + lbase]);
            }
        }
        __builtin_amdgcn_sched_barrier(0);
        const f16* Ab = &lds[cur * 16384];
        const f16* Bb = &lds[32768 + cur * 16384];
#pragma unroll
        for (int ks = 0; ks < 2; ++ks) {
            const int kb = (ks*32 + lq*8) ^ swz;
            f16x8 bf[4];
#pragma unroll
            for (int nt = 0; nt < 4; ++nt)
                bf[nt] = *(const f16x8*)&Bb[(wc*64 + nt*16 + lr)*64 + kb];
#pragma unroll
            for (int mt = 0; mt < 8; ++mt) {
                f16x8 af = *(const f16x8*)&Ab[(wr*128 + mt*16 + lr)*64 + kb];
#pragma unroll
                for (int nt = 0; nt < 4; ++nt)
                    acc[mt][nt] = __builtin_amdgcn_mfma_f32_16x16x32_f16(
                        af, bf[nt], acc[mt][nt], 0, 0, 0);
            }
        }
        asm volatile("s_waitcnt vmcnt(0)" ::: "memory");
        __builtin_amdgcn_sched_barrier(0);
        __builtin_amdgcn_s_barrier();
        cur ^= 1;
    }

    if (mode == 0) {
        const int mat   = n0 / EDIM;
        const int hbase = ((n0 % EDIM) >> 6) + wc;
        f16* dst = (mat == 0) ? q_o : (mat == 1) ? k_o : v_o;
        f16* scr = &lds[w * 2304];
#pragma unroll
        for (int mt2 = 0; mt2 < 4; ++mt2) {
#pragma unroll
            for (int mtp = 0; mtp < 2; ++mtp) {
                const int mt = mt2*2 + mtp;
#pragma unroll
                for (int nt = 0; nt < 4; ++nt)
#pragma unroll
                    for (int rg = 0; rg < 4; ++rg)
                        scr[(mtp*16 + lq*4 + rg)*72 + nt*16 + lr] = (f16)acc[mt][nt][rg];
            }
            wfence();
#pragma unroll
            for (int i = 0; i < 4; ++i) {
                int row = (l >> 3) + i*8;
                f16x8 v = *(const f16x8*)&scr[row*72 + (l & 7)*8];
                int R = m0 + wr*128 + mt2*32 + row;
                if (R < MROWS) {
                    int bb = R / NTOK, nn = R - bb*NTOK;
                    *(f16x8*)&dst[((size_t)(bb*NH + hbase)*NTOK + nn)*HDIM + (l & 7)*8] = v;
                }
            }
            wfence();
        }
    } else {
#pragma unroll
        for (int mt = 0; mt < 8; ++mt)
#pragma unroll
            for (int rg = 0; rg < 4; ++rg) {
                int R = m0 + wr*128 + mt*16 + lq*4 + rg;
                if (R < MROWS) {
                    float* base = p_o + (size_t)R * EDIM + n0 + wc*64;
#pragma unroll
                    for (int nt = 0; nt < 4; ++nt) {
                        int c = nt*16 + lr;
                        base[c] = acc[mt][nt][rg] + bias[n0 + wc*64 + c];
                    }
                }
            }
    }
}

// ---------------------------------------------------------------------------
// MFMA fused attention v7 (round-12, kept): Kle+Gt via global_load_lds 1KB
// chunks (linear dest, pre-swizzled source); Vt gather load-early/write-late.
// ---------------------------------------------------------------------------
#define SKE 128
#define SVT 320
#define SGT 256
#define SWS 72
#define ATHR 832

__global__ __launch_bounds__(ATHR, 1) void attn_mfma(
    const f16* __restrict__ q_ws, const f16* __restrict__ k_ws,
    const f16* __restrict__ v_ws,
    const float* __restrict__ rvv, const float* __restrict__ rvh,
    const f16* __restrict__ gA, const f16* __restrict__ gt_buf,
    f16* __restrict__ o_ws)
{
    __shared__ f16 Kle[272*SKE];     // 69632 B = 68 chunks
    __shared__ f16 Vt[64*SVT];       // 40960 B
    __shared__ f16 Gt[32*SGT];       // 16384 B = 16 chunks
    __shared__ f16 WSh[13*16*SWS];   // 29952 B  (total 156928 B)

    const int tid = threadIdx.x;
    const int w = tid >> 6, l = tid & 63;
    const int lr = l & 15, lq = l >> 4;
    const int bh = blockIdx.x;
    const int b = bh / NH, h = bh - b * NH;
    const f16* Qp = q_ws + (size_t)bh * NTOK * HDIM;
    const f16* Kp = k_ws + (size_t)bh * NTOK * HDIM;
    const f16* Vp = v_ws + (size_t)bh * NTOK * HDIM;
    f16* wsh = &WSh[w * 16 * SWS];

    for (int c = w; c < 84; c += 13) {
        f16* ldsb;
        const f16* gsrc;
        if (c < 68) {
            int idx = c*64 + l;
            int row = idx >> 4, cs8 = (idx & 15) << 3;
            ldsb = &Kle[c * 512];
            gsrc = (row < NTOK && cs8 < 64)
                 ? (Kp + row*64 + (cs8 ^ ((row & 7) << 3)))
                 : (gA + row*SKE + cs8);
        } else {
            int c2 = c - 68;
            ldsb = &Gt[c2 * 512];
            gsrc = gt_buf + c2*512 + l*8;
        }
        gload16(gsrc, ldsb);
    }

    f16x8 vbuf[4];
#pragma unroll
    for (int it = 0; it < 4; ++it) {
        int idx = tid + it*ATHR;
        if (idx < 8*SVT) {
            int dlow = idx & 7, k = idx >> 3;
            bool isV = (k < NTOK), isA = (k >= 208 && k < 238), isB = (k >= 238 && k < 268);
#pragma unroll
            for (int e = 0; e < 8; ++e) {
                int d = (e << 3) + dlow;
                f16 val = (f16)0.f;
                if (isV)      val = Vp[k*64 + d];
                else if (isA) val = (f16)rvv[(k-208)*64 + d];
                else if (isB) val = (f16)rvh[(k-238)*64 + d];
                vbuf[it][e] = val;
            }
        }
    }

    const int tt = w;
    const int i0 = tt * 16;
    const int iq = i0 + lr;
    const int iqc = (iq > 196) ? 196 : iq;
    const f16* qsrc = Qp + iqc*64 + lq*8;
    f16x8 qf0 = *(const f16x8*)qsrc;
    f16x8 qf1 = *(const f16x8*)(qsrc + 32);

    __syncthreads();

    const int src0 = ((l >> 4) & 1) * 32 + lr;
    const int src1 = src0 + 16;
    const int sw = (lr & 7) << 3;

    {
        __builtin_amdgcn_s_setprio(1);
        f32x4 pacc[4];
#pragma unroll
        for (int ct = 0; ct < 4; ++ct) {
            f32x4 a; a[0]=0.f; a[1]=0.f; a[2]=0.f; a[3]=0.f;
            const int krow = (13+ct)*16 + lr;
            f16x8 kf0 = *(f16x8*)&Kle[krow*SKE + ((lq*8) ^ sw)];
            f16x8 kf1 = *(f16x8*)&Kle[krow*SKE + ((32 + lq*8) ^ sw)];
            a = __builtin_amdgcn_mfma_f32_16x16x32_f16(kf0, qf0, a, 0, 0, 0);
            a = __builtin_amdgcn_mfma_f32_16x16x32_f16(kf1, qf1, a, 0, 0, 0);
            pacc[ct] = a;
        }
        __builtin_amdgcn_s_setprio(0);
#pragma unroll
        for (int ct = 0; ct < 4; ++ct)
#pragma unroll
            for (int rg = 0; rg < 4; ++rg)
                wsh[lr*SWS + ct*16 + lq*4 + rg] = (f16)pacc[ct][rg];
        wfence();

        int id_ = 0, ih_ = 0;
        const bool qcls = (iq == 0);
        if (iq > 0) { unsigned v = div14((unsigned)(iq-1)); id_ = (int)v; ih_ = (iq-1) - (int)v*14; }
        f16x8 qcf;
#pragma unroll
        for (int e = 0; e < 8; ++e) {
            int g = lq*8 + e;
            int toff;
            if (g < 14)       toff = qcls ? 0 : (g - id_ + 15);
            else if (g == 14) toff = 0;
            else if (g == 15) toff = 63;
            else if (g < 30)  toff = qcls ? 32 : (32 + (g-16) - ih_ + 15);
            else if (g == 30) toff = 32;
            else              toff = 63;
            qcf[e] = wsh[lr*SWS + toff];
        }

        f32x4 acc[13];
        __builtin_amdgcn_s_setprio(1);
#pragma unroll
        for (int ct = 0; ct < 13; ++ct) {
            f32x4 a; a[0]=0.f; a[1]=0.f; a[2]=0.f; a[3]=0.f;
            const int krow = ct*16 + lr;
            f16x8 kf0 = *(f16x8*)&Kle[krow*SKE + ((lq*8) ^ sw)];
            f16x8 kf1 = *(f16x8*)&Kle[krow*SKE + ((32 + lq*8) ^ sw)];
            f16x8 gf  = *(f16x8*)&Kle[krow*SKE + ((64 + lq*8) ^ sw)];
            a = __builtin_amdgcn_mfma_f32_16x16x32_f16(kf0, qf0, a, 0, 0, 0);
            a = __builtin_amdgcn_mfma_f32_16x16x32_f16(kf1, qf1, a, 0, 0, 0);
            a = __builtin_amdgcn_mfma_f32_16x16x32_f16(gf,  qcf, a, 0, 0, 0);
            acc[ct] = a;
        }
        __builtin_amdgcn_s_setprio(0);

#pragma unroll
        for (int rg = 0; rg < 4; ++rg)
            if (lq*4 + rg > 4) acc[12][rg] = -1e30f;

        float m = -1e30f;
#pragma unroll
        for (int ct = 0; ct < 13; ++ct)
#pragma unroll
            for (int rg = 0; rg < 4; ++rg) m = fmaxf(m, acc[ct][rg]);
        m = fmaxf(m, __shfl_xor(m, 16));
        m = fmaxf(m, __shfl_xor(m, 32));
        const float C1 = 0.125f * 1.44269504088896f;
        const float nm = -m * C1;
        float ssum = 0.f;
#pragma unroll
        for (int ct = 0; ct < 13; ++ct)
#pragma unroll
            for (int rg = 0; rg < 4; ++rg) {
                float p = exp2f(fmaf(acc[ct][rg], C1, nm));
                acc[ct][rg] = p; ssum += p;
            }
        ssum += __shfl_xor(ssum, 16);
        ssum += __shfl_xor(ssum, 32);
        const float inv = 1.f / ssum;
        const float pn00 = acc[0][0] * inv;

        unsigned pk[13][2];
#pragma unroll
        for (int ct = 0; ct < 13; ++ct) {
            union { f16x4 hh; unsigned u[2]; } t;
            t.hh[0] = (f16)(acc[ct][0] * inv);
            t.hh[1] = (f16)(acc[ct][1] * inv);
            t.hh[2] = (f16)(acc[ct][2] * inv);
            t.hh[3] = (f16)(acc[ct][3] * inv);
            pk[ct][0] = t.u[0]; pk[ct][1] = t.u[1];
        }

        f16x8 pa[7];
#pragma unroll
        for (int kc = 0; kc < 7; ++kc) {
            const int ctA = 2*kc;
            const int ctB = (kc == 6) ? 12 : 2*kc + 1;
            unsigned A0 = (unsigned)__shfl((int)pk[ctA][0], src0);
            unsigned A1 = (unsigned)__shfl((int)pk[ctA][1], src0);
            unsigned A2 = (unsigned)__shfl((int)pk[ctA][0], src1);
            unsigned A3 = (unsigned)__shfl((int)pk[ctA][1], src1);
            unsigned B0 = (unsigned)__shfl((int)pk[ctB][0], src0);
            unsigned B1 = (unsigned)__shfl((int)pk[ctB][1], src0);
            unsigned B2 = (unsigned)__shfl((int)pk[ctB][0], src1);
            unsigned B3 = (unsigned)__shfl((int)pk[ctB][1], src1);
            bool hiHalf = (lq >= 2);
            union { unsigned u[4]; f16x8 v; } f;
            f.u[0] = hiHalf ? B0 : A0;
            f.u[1] = hiHalf ? B1 : A1;
            f.u[2] = hiHalf ? B2 : A2;
            f.u[3] = hiHalf ? B3 : A3;
            if (kc == 6 && hiHalf) { f.u[0]=0; f.u[1]=0; f.u[2]=0; f.u[3]=0; }
            pa[kc] = f.v;
        }

        f32x4 gacc[2];
#pragma unroll
        for (int ct = 0; ct < 2; ++ct) { gacc[ct][0]=0.f; gacc[ct][1]=0.f; gacc[ct][2]=0.f; gacc[ct][3]=0.f; }
        __builtin_amdgcn_s_setprio(1);
#pragma unroll
        for (int kc = 0; kc < 7; ++kc) {
#pragma unroll
            for (int ct = 0; ct < 2; ++ct) {
                f16x8 gf = *(f16x8*)&Gt[(ct*16 + lr)*SGT + ((kc*32 + lq*8) ^ sw)];
                gacc[ct] = __builtin_amdgcn_mfma_f32_16x16x32_f16(pa[kc], gf, gacc[ct], 0, 0, 0);
            }
        }
        __builtin_amdgcn_s_setprio(0);

#pragma unroll
        for (int z = 0; z < 2; ++z) {
            int zi = z*64 + l;
            int zr = zi >> 3, zc = (zi & 7) << 3;
            f16x8 zz;
#pragma unroll
            for (int e = 0; e < 8; ++e) zz[e] = (f16)0.f;
            *(f16x8*)&wsh[zr*SWS + zc] = zz;
        }
        wfence();
#pragma unroll
        for (int rg = 0; rg < 4; ++rg) {
            int il = lq*4 + rg;
            int is_ = i0 + il;
            if (lr < 14 && is_ > 0) {
                unsigned v = div14((unsigned)(is_-1));
                int id2 = (int)v, ih2 = (is_-1) - (int)v*14;
                wsh[il*SWS + (lr - id2 + 15)]      = (f16)gacc[0][rg];
                wsh[il*SWS + 30 + (lr - ih2 + 15)] = (f16)gacc[1][rg];
            }
        }
        if (lq == 0 && !(i0 == 0 && lr == 0)) {
            wsh[lr*SWS + 0]  = (f16)pn00;
            wsh[lr*SWS + 30] = (f16)pn00;
        }
        if (i0 == 0) {
            float sv = (lq == 0) ? gacc[0][0] : 0.f;
            float sh = (lq == 0) ? gacc[1][0] : 0.f;
            sv += __shfl_xor(sv, 1); sv += __shfl_xor(sv, 2);
            sv += __shfl_xor(sv, 4); sv += __shfl_xor(sv, 8);
            sh += __shfl_xor(sh, 1); sh += __shfl_xor(sh, 2);
            sh += __shfl_xor(sh, 4); sh += __shfl_xor(sh, 8);
            if (l == 0) {
                wsh[0]  = (f16)(sv + pn00);
                wsh[30] = (f16)(sh + pn00);
            }
        }
        wfence();

#pragma unroll
        for (int it = 0; it < 4; ++it) {
            int idx = tid + it*ATHR;
            if (idx < 8*SVT) {
                int dlow = idx & 7, k = idx >> 3;
                int kx = k ^ (dlow << 3);
#pragma unroll
                for (int e = 0; e < 8; ++e)
                    Vt[((e << 3) + dlow)*SVT + kx] = vbuf[it][e];
            }
        }
        __syncthreads();

        f16x8 sfr[2];
#pragma unroll
        for (int kc2 = 0; kc2 < 2; ++kc2)
            sfr[kc2] = *(f16x8*)&wsh[lr*SWS + kc2*32 + lq*8];

        f32x4 oacc[4];
#pragma unroll
        for (int ct = 0; ct < 4; ++ct) { oacc[ct][0]=0.f; oacc[ct][1]=0.f; oacc[ct][2]=0.f; oacc[ct][3]=0.f; }
        __builtin_amdgcn_s_setprio(1);
#pragma unroll
        for (int kc = 0; kc < 7; ++kc) {
#pragma unroll
            for (int ct = 0; ct < 4; ++ct) {
                f16x8 vf = *(f16x8*)&Vt[(ct*16 + lr)*SVT + ((kc*32 + lq*8) ^ sw)];
                oacc[ct] = __builtin_amdgcn_mfma_f32_16x16x32_f16(pa[kc], vf, oacc[ct], 0, 0, 0);
            }
        }
#pragma unroll
        for (int kc2 = 0; kc2 < 2; ++kc2) {
#pragma unroll
            for (int ct = 0; ct < 4; ++ct) {
                f16x8 vf = *(f16x8*)&Vt[(ct*16 + lr)*SVT + ((208 + kc2*32 + lq*8) ^ sw)];
                oacc[ct] = __builtin_amdgcn_mfma_f32_16x16x32_f16(sfr[kc2], vf, oacc[ct], 0, 0, 0);
            }
        }
        __builtin_amdgcn_s_setprio(0);

#pragma unroll
        for (int ct = 0; ct < 4; ++ct)
#pragma unroll
            for (int rg = 0; rg < 4; ++rg) {
                int io = i0 + lq*4 + rg;
                if (io < NTOK) {
                    int d = ct*16 + lr;
                    o_ws[((size_t)(b * NTOK + io) * NH + h) * HDIM + d] = (f16)oacc[ct][rg];
                }
            }
    }
}

extern "C" void kernel_launch(void* const* d_in, const int* in_sizes, int n_in,
                              void* d_out, int out_size, void* d_ws, size_t ws_size,
                              hipStream_t stream)
{
    const float* x     = (const float*)d_in[0];
    const float* wq    = (const float*)d_in[1];
    const float* wk    = (const float*)d_in[2];
    const float* wv    = (const float*)d_in[3];
    const float* wproj = (const float*)d_in[4];
    const float* bproj = (const float*)d_in[5];
    const float* rkv   = (const float*)d_in[6];
    const float* rkh   = (const float*)d_in[7];
    const float* rvv   = (const float*)d_in[8];
    const float* rvh   = (const float*)d_in[9];

    f16* ws = (f16*)d_ws;
    const size_t sz = (size_t)MROWS * EDIM;
    f16* xh    = ws;
    f16* qh    = xh + sz;
    f16* kh    = qh + sz;
    f16* vh    = kh + sz;
    f16* oh    = vh + sz;
    f16* wqkvT = oh + sz;                          // 3*768*768
    f16* wpT   = wqkvT + (size_t)3*EDIM*EDIM;      // 768*768
    f16* gA    = wpT   + (size_t)EDIM*EDIM;        // 272*128 (pre-swizzled)
    f16* gtb   = gA    + 272*128;                  // 32*256  (pre-swizzled)

    prep_all<<<5336, 256, 0, stream>>>(x, wq, wk, wv, wproj, rkv, rkh,
                                       xh, wqkvT, wpT, gA, gtb);
    gemm256 <<<50*9, 512, 0, stream>>>(xh, wqkvT, qh, kh, vh,
                                       nullptr, nullptr, 0, 9);
    attn_mfma<<<NB * NH, ATHR, 0, stream>>>(qh, kh, vh,
                                            rvv, rvh, gA, gtb, oh);
    gemm256 <<<50*3, 512, 0, stream>>>(oh, wpT, nullptr, nullptr, nullptr,
                                       (float*)d_out, bproj, 1, 3);
}